// Round 3
// baseline (1379.105 us; speedup 1.0000x reference)
//
#include <hip/hip_runtime.h>

// ---------------- preprocessing kernels ----------------

__global__ void k_deg(const int* __restrict__ col, int* __restrict__ indeg, int E){
  int e = blockIdx.x*blockDim.x + threadIdx.x;
  if (e < E) atomicAdd(&indeg[col[e]], 1);
}

__global__ void k_dinv(const int* __restrict__ indeg, float* __restrict__ dinv, int n){
  int i = blockIdx.x*blockDim.x + threadIdx.x;
  if (i < n) dinv[i] = rsqrtf((float)(indeg[i] + 1));
}

__global__ __launch_bounds__(256) void k_scan1(const int* __restrict__ indeg, int* __restrict__ rp,
                                               int* __restrict__ bsums, int n){
  __shared__ int s[256];
  int b = blockIdx.x, t = threadIdx.x;
  int base = b*1024 + t*4;
  int v[4]; int tsum = 0;
  #pragma unroll
  for (int j=0;j<4;j++){ v[j] = (base+j < n) ? indeg[base+j] : 0; tsum += v[j]; }
  s[t] = tsum; __syncthreads();
  for (int d=1; d<256; d<<=1){ int x = (t>=d) ? s[t-d] : 0; __syncthreads(); s[t] += x; __syncthreads(); }
  int run = s[t] - tsum;
  if (t == 255) bsums[b] = s[255];
  #pragma unroll
  for (int j=0;j<4;j++){ if (base+j < n){ rp[base+j] = run; } run += v[j]; }
}

__global__ __launch_bounds__(128) void k_scan2(int* bsums, int* rp, int nb, int n){
  __shared__ int s[128];
  int t = threadIdx.x;
  int orig = (t < nb) ? bsums[t] : 0;
  s[t] = orig; __syncthreads();
  for (int d=1; d<128; d<<=1){ int x = (t>=d) ? s[t-d] : 0; __syncthreads(); s[t] += x; __syncthreads(); }
  if (t < nb) bsums[t] = s[t] - orig;
  if (t == 127) rp[n] = s[127];
}

__global__ void k_scan3(int* __restrict__ rp, int* __restrict__ nxt, const int* __restrict__ bsums, int n){
  int i = blockIdx.x*blockDim.x + threadIdx.x;
  if (i < n){ int v = rp[i] + bsums[i >> 10]; rp[i] = v; nxt[i] = v; }
}

__global__ void k_scatter(const int* __restrict__ row, const int* __restrict__ col,
                          int* __restrict__ nxt, int* __restrict__ csr, int E){
  int e = blockIdx.x*blockDim.x + threadIdx.x;
  if (e < E){ int c = col[e]; int p = atomicAdd(&nxt[c], 1); csr[p] = row[e]; }
}

// ---------------- x restage: 75-wide -> 80-stride zero-padded ----------------

__global__ void k_pad(const float* __restrict__ x, float* __restrict__ xp, int n){
  long total = (long)n * 80;
  for (long idx = blockIdx.x*(long)blockDim.x + threadIdx.x; idx < total; idx += (long)gridDim.x*blockDim.x){
    int r = (int)(idx / 80), f = (int)(idx % 80);
    xp[idx] = (f < 75) ? x[(size_t)r*75 + f] : 0.0f;
  }
}

// ---------------- sparse propagation: out = D^-1/2 (A+I) D^-1/2 h ----------------
// pull-based, one wave per node, lane loads float4; 4-edge batched gathers

template<int FP>  // padded feature width, multiple of 4; pads are zero
__global__ __launch_bounds__(256) void k_prop(const float* __restrict__ h, const float* __restrict__ dinv,
                                              const int* __restrict__ rp, const int* __restrict__ csr,
                                              float* __restrict__ out, int n){
  int node = blockIdx.x*4 + (threadIdx.x >> 6);
  int lane = threadIdx.x & 63;
  if (node >= n) return;
  int f = 4*lane;
  bool act = (f < FP);
  float di = dinv[node];
  float4 acc = make_float4(0.f,0.f,0.f,0.f);
  if (act){
    float4 v = *(const float4*)&h[(size_t)node*FP + f];
    acc.x = di*v.x; acc.y = di*v.y; acc.z = di*v.z; acc.w = di*v.w;
  }
  int e0 = rp[node], e1 = rp[node+1];
  int e = e0;
  for (; e + 4 <= e1; e += 4){
    int s0 = csr[e], s1 = csr[e+1], s2 = csr[e+2], s3 = csr[e+3];
    float d0 = dinv[s0], d1 = dinv[s1], d2 = dinv[s2], d3 = dinv[s3];
    if (act){
      float4 v0 = *(const float4*)&h[(size_t)s0*FP + f];
      float4 v1 = *(const float4*)&h[(size_t)s1*FP + f];
      float4 v2 = *(const float4*)&h[(size_t)s2*FP + f];
      float4 v3 = *(const float4*)&h[(size_t)s3*FP + f];
      acc.x += d0*v0.x + d1*v1.x + d2*v2.x + d3*v3.x;
      acc.y += d0*v0.y + d1*v1.y + d2*v2.y + d3*v3.y;
      acc.z += d0*v0.z + d1*v1.z + d2*v2.z + d3*v3.z;
      acc.w += d0*v0.w + d1*v1.w + d2*v2.w + d3*v3.w;
    }
  }
  for (; e < e1; ++e){
    int s = csr[e]; float ds = dinv[s];
    if (act){
      float4 v = *(const float4*)&h[(size_t)s*FP + f];
      acc.x += ds*v.x; acc.y += ds*v.y; acc.z += ds*v.z; acc.w += ds*v.w;
    }
  }
  if (act){
    float4 o; o.x = di*acc.x; o.y = di*acc.y; o.z = di*acc.z; o.w = di*acc.w;
    *(float4*)&out[(size_t)node*FP + f] = o;
  }
}

// ---------------- tiled f32 GEMM: C = [relu](A@W + b), optional fused max-pool ----------------
// BM=256 x BN=64 tile, 256 threads, 8x8 acc/thread, BK=16, A staged transposed.
// A rows have stride lda (>= Kpad, mult of 4, zero-padded cols). Kpad mult of 16.

__global__ __launch_bounds__(256) void k_gemm(
    const float* __restrict__ A, int lda,
    const float* __restrict__ W, int NC,          // W is Kreal x NC, row stride NC
    const float* __restrict__ bias,
    float* __restrict__ Cout, int ldc,            // also gpool stride when pool=1
    const int* __restrict__ batch, unsigned* __restrict__ gpool,
    int n, int Kpad, int Kreal, int NCpad, int relu, int pool, int G)
{
  __shared__ float AsT[16][260];   // [kk][row], stride 260 -> 2-way-free banks, 16B aligned
  __shared__ float Ws[16][68];
  __shared__ unsigned pmax[4][64];
  int r0 = blockIdx.x * 256, c0 = blockIdx.y * 64;
  int tid = threadIdx.x;
  int tx = tid & 7, ty = tid >> 3;          // 8 cols x 32 row-groups
  int kq = tid & 3, rr = tid >> 2;          // A staging: 4 k-quads x 64 rows
  int cw = 4*(tid & 15), kw = tid >> 4;     // W staging

  float acc[8][8];
  #pragma unroll
  for (int u=0;u<8;u++)
    #pragma unroll
    for (int j=0;j<8;j++) acc[u][j] = 0.f;

  for (int k0 = 0; k0 < Kpad; k0 += 16){
    // stage A (transposed): 256x16
    #pragma unroll
    for (int p=0;p<4;p++){
      int r = rr + 64*p;
      float4 v = make_float4(0.f,0.f,0.f,0.f);
      if (r0 + r < n) v = *(const float4*)&A[(size_t)(r0+r)*lda + k0 + 4*kq];
      AsT[4*kq+0][r] = v.x; AsT[4*kq+1][r] = v.y; AsT[4*kq+2][r] = v.z; AsT[4*kq+3][r] = v.w;
    }
    // stage W: 16x64 (scalar guarded reads; NC may be odd / edge tiles)
    {
      int krow = k0 + kw;
      float4 wv;
      wv.x = (krow < Kreal && c0+cw+0 < NC) ? W[(size_t)krow*NC + c0+cw+0] : 0.f;
      wv.y = (krow < Kreal && c0+cw+1 < NC) ? W[(size_t)krow*NC + c0+cw+1] : 0.f;
      wv.z = (krow < Kreal && c0+cw+2 < NC) ? W[(size_t)krow*NC + c0+cw+2] : 0.f;
      wv.w = (krow < Kreal && c0+cw+3 < NC) ? W[(size_t)krow*NC + c0+cw+3] : 0.f;
      *(float4*)&Ws[kw][cw] = wv;
    }
    __syncthreads();
    #pragma unroll
    for (int kk=0; kk<16; ++kk){
      float4 a0 = *(const float4*)&AsT[kk][8*ty];
      float4 a1 = *(const float4*)&AsT[kk][8*ty+4];
      float4 w0 = *(const float4*)&Ws[kk][8*tx];
      float4 w1 = *(const float4*)&Ws[kk][8*tx+4];
      float a[8] = {a0.x,a0.y,a0.z,a0.w,a1.x,a1.y,a1.z,a1.w};
      float w[8] = {w0.x,w0.y,w0.z,w0.w,w1.x,w1.y,w1.z,w1.w};
      #pragma unroll
      for (int u=0;u<8;u++)
        #pragma unroll
        for (int j=0;j<8;j++) acc[u][j] += a[u]*w[j];
    }
    __syncthreads();
  }

  if (!pool){
    #pragma unroll
    for (int u=0;u<8;u++){
      int r = r0 + 8*ty + u;
      if (r < n){
        #pragma unroll
        for (int j=0;j<8;j++){
          int c = c0 + 8*tx + j;
          if (c < NCpad){
            float v = 0.f;
            if (c < NC){
              v = acc[u][j] + bias[c];
              if (relu) v = fmaxf(v, 0.0f);
            }
            Cout[(size_t)r*ldc + c] = v;
          }
        }
      }
    }
  } else {
    // fused relu + segment-max pool (batch sorted, min graph size 195 -> <=3 graphs/256-row tile)
    if (tid < 256) pmax[tid>>6][tid&63] = 0u;
    __syncthreads();
    int g0 = batch[r0];
    int giu[8]; int rmax = 0;
    #pragma unroll
    for (int u=0;u<8;u++){
      int r = r0 + 8*ty + u;
      if (r < n){ int gi = batch[r] - g0; giu[u] = gi > 3 ? 3 : gi; rmax = u+1; }
    }
    #pragma unroll
    for (int j=0;j<8;j++){
      int c = c0 + 8*tx + j;
      if (c >= NC) continue;
      float b = bias[c];
      int curgi = -1; float m = 0.f;
      for (int u=0; u<rmax; ++u){
        int gi = giu[u];
        float v = fmaxf(acc[u][j] + b, 0.f);
        if (gi != curgi){
          if (curgi >= 0 && m > 0.f) atomicMax(&pmax[curgi][8*tx+j], __float_as_uint(m));
          curgi = gi; m = v;
        } else m = fmaxf(m, v);
      }
      if (curgi >= 0 && m > 0.f) atomicMax(&pmax[curgi][8*tx+j], __float_as_uint(m));
    }
    __syncthreads();
    {
      int gi = tid >> 6, c = tid & 63;
      unsigned v = pmax[gi][c];
      int gg = g0 + gi;
      if (v != 0u && (c0 + c) < NC && gg < G)
        atomicMax(&gpool[(size_t)gg*ldc + (c0 + c)], v);
    }
  }
}

// ---------------- final MLP layer: out[row] = gh[row] @ Wg2 + bg2 (512x1024 @ 1024x128) ----------------

__global__ __launch_bounds__(256) void k_mlp2(const float* __restrict__ gh, const float* __restrict__ W,
                                              const float* __restrict__ b, float* __restrict__ out){
  __shared__ float s[1024];
  __shared__ float red[256];
  int row = blockIdx.x; int tid = threadIdx.x;
  for (int k = tid; k < 1024; k += 256) s[k] = gh[(size_t)row*1024 + k];
  __syncthreads();
  int c = tid & 127, h = tid >> 7;
  float acc = 0.f;
  for (int k = h*512; k < h*512 + 512; ++k) acc += s[k] * W[(size_t)k*128 + c];
  red[tid] = acc; __syncthreads();
  if (h == 0) out[(size_t)row*128 + c] = red[c] + red[128 + c] + b[c];
}

// ---------------- launcher ----------------

extern "C" void kernel_launch(void* const* d_in, const int* in_sizes, int n_in,
                              void* d_out, int out_size, void* d_ws, size_t ws_size,
                              hipStream_t stream)
{
  const float* x   = (const float*)d_in[0];
  const int*   ei  = (const int*)d_in[1];
  const int*   batch = (const int*)d_in[2];
  const float* W1  = (const float*)d_in[3]; const float* b1  = (const float*)d_in[4];
  const float* W2  = (const float*)d_in[5]; const float* b2  = (const float*)d_in[6];
  const float* W3  = (const float*)d_in[7]; const float* b3  = (const float*)d_in[8];
  const float* Wg1 = (const float*)d_in[9]; const float* bg1 = (const float*)d_in[10];
  const float* Wg2 = (const float*)d_in[11]; const float* bg2 = (const float*)d_in[12];
  float* out = (float*)d_out;

  const int F1 = 75;
  int n = in_sizes[0] / F1;          // 100000
  int E = in_sizes[1] / 2;           // 800000
  int G = out_size / 128;            // 512
  const int* row = ei;
  const int* col = ei + E;

  char* ws = (char*)d_ws;
  size_t off = 0;
  auto alloc = [&](size_t bytes){ size_t o = off; off += (bytes + 255) & ~(size_t)255; return o; };
  float* xp    = (float*)(ws + alloc((size_t)n*80*4));   // padded x; aliased as bufH1 after prop1
  float* bufQ  = (float*)(ws + alloc((size_t)n*160*4));  // propagated features (<=160 stride)
  float* bufH2 = (float*)(ws + alloc((size_t)n*160*4));  // h2 (stride 160)
  float* dinv  = (float*)(ws + alloc((size_t)n*4));
  int*   indeg = (int*)  (ws + alloc((size_t)n*4));
  int*   rp    = (int*)  (ws + alloc((size_t)(n+1)*4));
  int*   nxt   = (int*)  (ws + alloc((size_t)n*4));
  int*   csr   = (int*)  (ws + alloc((size_t)E*4));
  int*   bsums = (int*)  (ws + alloc(1024*4));
  unsigned* g  = (unsigned*)(ws + alloc((size_t)G*320*4)); // pooled (stride 320, zero-padded)
  float* gh    = (float*)(ws + alloc((size_t)G*1024*4));
  float* bufH1 = xp;                                      // alias: xp dead after prop1

  hipMemsetAsync(indeg, 0, (size_t)n*4, stream);
  hipMemsetAsync(g, 0, (size_t)G*320*4, stream);

  k_deg<<<(E+255)/256, 256, 0, stream>>>(col, indeg, E);
  k_dinv<<<(n+255)/256, 256, 0, stream>>>(indeg, dinv, n);

  int nb = (n + 1023) / 1024;
  k_scan1<<<nb, 256, 0, stream>>>(indeg, rp, bsums, n);
  k_scan2<<<1, 128, 0, stream>>>(bsums, rp, nb, n);
  k_scan3<<<(n+255)/256, 256, 0, stream>>>(rp, nxt, bsums, n);
  k_scatter<<<(E+255)/256, 256, 0, stream>>>(row, col, nxt, csr, E);

  k_pad<<<4096, 256, 0, stream>>>(x, xp, n);

  int pb = (n + 3) / 4;
  int rb = (n + 255) / 256;   // 391

  // layer 1: q = Ahat xp ; h1 = relu(q@W1 + b1)   [K 75->80, NC 75->80]
  k_prop<80><<<pb, 256, 0, stream>>>(xp, dinv, rp, csr, bufQ, n);
  {
    dim3 grid(rb, 2);
    k_gemm<<<grid, 256, 0, stream>>>(bufQ, 80, W1, 75, b1, bufH1, 80,
                                     nullptr, nullptr, n, 80, 75, 80, 1, 0, G);
  }
  // layer 2   [K 75->80, NC 150->160]
  k_prop<80><<<pb, 256, 0, stream>>>(bufH1, dinv, rp, csr, bufQ, n);
  {
    dim3 grid(rb, 3);
    k_gemm<<<grid, 256, 0, stream>>>(bufQ, 80, W2, 150, b2, bufH2, 160,
                                     nullptr, nullptr, n, 80, 75, 160, 1, 0, G);
  }
  // layer 3 + fused relu + segment-max pool -> g (stride 320)   [K 150->160]
  k_prop<160><<<pb, 256, 0, stream>>>(bufH2, dinv, rp, csr, bufQ, n);
  {
    dim3 grid(rb, 5);
    k_gemm<<<grid, 256, 0, stream>>>(bufQ, 160, W3, 300, b3, (float*)g, 320,
                                     batch, g, n, 160, 150, 320, 1, 1, G);
  }
  // MLP head: gh = relu(g @ Wg1 + bg1)   [K 300->320]
  {
    dim3 grid((G + 255)/256, 16);
    k_gemm<<<grid, 256, 0, stream>>>((const float*)g, 320, Wg1, 1024, bg1, gh, 1024,
                                     nullptr, nullptr, G, 320, 300, 1024, 1, 0, G);
  }
  k_mlp2<<<G, 256, 0, stream>>>(gh, Wg2, bg2, out);
}

// Round 4
// 829.585 us; speedup vs baseline: 1.6624x; 1.6624x over previous
//
#include <hip/hip_runtime.h>

typedef __attribute__((ext_vector_type(8))) short short8v;   // 8 bf16
typedef __attribute__((ext_vector_type(4))) float f32x4;

__device__ inline unsigned short f2bf(float x){
  union{float f; unsigned u;} v; v.f = x;
  unsigned r = (v.u + 0x7FFFu + ((v.u >> 16) & 1u)) >> 16;
  return (unsigned short)r;
}

// ---------------- preprocessing kernels ----------------

__global__ void k_deg(const int* __restrict__ col, int* __restrict__ indeg, int E){
  int e = blockIdx.x*blockDim.x + threadIdx.x;
  if (e < E) atomicAdd(&indeg[col[e]], 1);
}

__global__ void k_dinv(const int* __restrict__ indeg, float* __restrict__ dinv, int n){
  int i = blockIdx.x*blockDim.x + threadIdx.x;
  if (i < n) dinv[i] = rsqrtf((float)(indeg[i] + 1));
}

__global__ __launch_bounds__(256) void k_scan1(const int* __restrict__ indeg, int* __restrict__ rp,
                                               int* __restrict__ bsums, int n){
  __shared__ int s[256];
  int b = blockIdx.x, t = threadIdx.x;
  int base = b*1024 + t*4;
  int v[4]; int tsum = 0;
  #pragma unroll
  for (int j=0;j<4;j++){ v[j] = (base+j < n) ? indeg[base+j] : 0; tsum += v[j]; }
  s[t] = tsum; __syncthreads();
  for (int d=1; d<256; d<<=1){ int x = (t>=d) ? s[t-d] : 0; __syncthreads(); s[t] += x; __syncthreads(); }
  int run = s[t] - tsum;
  if (t == 255) bsums[b] = s[255];
  #pragma unroll
  for (int j=0;j<4;j++){ if (base+j < n){ rp[base+j] = run; } run += v[j]; }
}

__global__ __launch_bounds__(128) void k_scan2(int* bsums, int* rp, int nb, int n){
  __shared__ int s[128];
  int t = threadIdx.x;
  int orig = (t < nb) ? bsums[t] : 0;
  s[t] = orig; __syncthreads();
  for (int d=1; d<128; d<<=1){ int x = (t>=d) ? s[t-d] : 0; __syncthreads(); s[t] += x; __syncthreads(); }
  if (t < nb) bsums[t] = s[t] - orig;
  if (t == 127) rp[n] = s[127];
}

__global__ void k_scan3(int* __restrict__ rp, int* __restrict__ nxt, const int* __restrict__ bsums, int n){
  int i = blockIdx.x*blockDim.x + threadIdx.x;
  if (i < n){ int v = rp[i] + bsums[i >> 10]; rp[i] = v; nxt[i] = v; }
}

__global__ void k_scatter(const int* __restrict__ row, const int* __restrict__ col,
                          int* __restrict__ nxt, int* __restrict__ csr, int E){
  int e = blockIdx.x*blockDim.x + threadIdx.x;
  if (e < E){ int c = col[e]; int p = atomicAdd(&nxt[c], 1); csr[p] = row[e]; }
}

// x restage: 75-wide -> 80-stride zero-padded
__global__ void k_pad(const float* __restrict__ x, float* __restrict__ xp, int n){
  long total = (long)n * 80;
  for (long idx = blockIdx.x*(long)blockDim.x + threadIdx.x; idx < total; idx += (long)gridDim.x*blockDim.x){
    int r = (int)(idx / 80), f = (int)(idx % 80);
    xp[idx] = (f < 75) ? x[(size_t)r*75 + f] : 0.0f;
  }
}

// W (f32, Kreal x NC) -> Wt (bf16, NCP x KPAD, transposed, zero-padded)
__global__ void k_wt(const float* __restrict__ W, unsigned short* __restrict__ Wt,
                     int Kreal, int NC, int KPAD, int NCP){
  int idx = blockIdx.x*blockDim.x + threadIdx.x;
  if (idx >= NCP*KPAD) return;
  int c = idx / KPAD, k = idx % KPAD;
  float v = (c < NC && k < Kreal) ? W[(size_t)k*NC + c] : 0.0f;
  Wt[idx] = f2bf(v);
}

// ---------------- sparse propagation: out = D^-1/2 (A+I) D^-1/2 h ----------------

template<int FP>
__global__ __launch_bounds__(256) void k_prop(const float* __restrict__ h, const float* __restrict__ dinv,
                                              const int* __restrict__ rp, const int* __restrict__ csr,
                                              float* __restrict__ out, int n){
  int node = blockIdx.x*4 + (threadIdx.x >> 6);
  int lane = threadIdx.x & 63;
  if (node >= n) return;
  int f = 4*lane;
  bool act = (f < FP);
  float di = dinv[node];
  float4 acc = make_float4(0.f,0.f,0.f,0.f);
  if (act){
    float4 v = *(const float4*)&h[(size_t)node*FP + f];
    acc.x = di*v.x; acc.y = di*v.y; acc.z = di*v.z; acc.w = di*v.w;
  }
  int e0 = rp[node], e1 = rp[node+1];
  int e = e0;
  for (; e + 4 <= e1; e += 4){
    int s0 = csr[e], s1 = csr[e+1], s2 = csr[e+2], s3 = csr[e+3];
    float d0 = dinv[s0], d1 = dinv[s1], d2 = dinv[s2], d3 = dinv[s3];
    if (act){
      float4 v0 = *(const float4*)&h[(size_t)s0*FP + f];
      float4 v1 = *(const float4*)&h[(size_t)s1*FP + f];
      float4 v2 = *(const float4*)&h[(size_t)s2*FP + f];
      float4 v3 = *(const float4*)&h[(size_t)s3*FP + f];
      acc.x += d0*v0.x + d1*v1.x + d2*v2.x + d3*v3.x;
      acc.y += d0*v0.y + d1*v1.y + d2*v2.y + d3*v3.y;
      acc.z += d0*v0.z + d1*v1.z + d2*v2.z + d3*v3.z;
      acc.w += d0*v0.w + d1*v1.w + d2*v2.w + d3*v3.w;
    }
  }
  for (; e < e1; ++e){
    int s = csr[e]; float ds = dinv[s];
    if (act){
      float4 v = *(const float4*)&h[(size_t)s*FP + f];
      acc.x += ds*v.x; acc.y += ds*v.y; acc.z += ds*v.z; acc.w += ds*v.w;
    }
  }
  if (act){
    float4 o; o.x = di*acc.x; o.y = di*acc.y; o.z = di*acc.z; o.w = di*acc.w;
    *(float4*)&out[(size_t)node*FP + f] = o;
  }
}

// ---------------- bf16 MFMA GEMM: out = relu(A@W + b) [f32 out], optional fused pool ----------------
// BM=128 x BN=64, 256 threads (4 waves), whole K staged once in LDS.
// A: f32, row stride KG (zero-padded cols). Wt: bf16 [NCP][KPAD] transposed, zero-padded.

template<int KPAD, int KG, int POOL>
__global__ __launch_bounds__(256) void k_gemm_mfma(
    const float* __restrict__ A, const unsigned short* __restrict__ Wt,
    const float* __restrict__ bias,
    float* __restrict__ out, int ldout, int NC,
    const int* __restrict__ batch, unsigned* __restrict__ gpool,
    int n, int G)
{
  constexpr int SA = KPAD + 8;
  constexpr int SW = KPAD + 8;
  __shared__ unsigned short As[128*SA];
  __shared__ unsigned short Ws[64*SW];
  __shared__ unsigned pmax[2][64];

  int tid = threadIdx.x;
  int r0 = blockIdx.x * 128, c0 = blockIdx.y * 64;
  int w = tid >> 6, l = tid & 63;

  // stage A (f32 -> bf16): 128 x KPAD
  {
    constexpr int C4 = KPAD/4;
    #pragma unroll
    for (int i = 0; i < 128*C4/256; ++i){
      int idx = tid + 256*i;
      int r = idx / C4, c4 = idx % C4;
      float4 v = make_float4(0.f,0.f,0.f,0.f);
      if (r0 + r < n && 4*c4 < KG) v = *(const float4*)&A[(size_t)(r0+r)*KG + 4*c4];
      unsigned p01 = (unsigned)f2bf(v.x) | ((unsigned)f2bf(v.y) << 16);
      unsigned p23 = (unsigned)f2bf(v.z) | ((unsigned)f2bf(v.w) << 16);
      *(uint2*)&As[r*SA + 4*c4] = make_uint2(p01, p23);
    }
  }
  // stage Wt tile: 64 x KPAD (bf16, already padded)
  {
    constexpr int K8 = KPAD/8;
    #pragma unroll
    for (int i = 0; i < 64*K8/256; ++i){
      int idx = tid + 256*i;
      int wr = idx / K8, wk = idx % K8;
      short8v wv = *(const short8v*)&Wt[(size_t)(c0+wr)*KPAD + 8*wk];
      *(short8v*)&Ws[wr*SW + 8*wk] = wv;
    }
  }
  if (POOL){ if (tid < 128) pmax[tid>>6][tid&63] = 0u; }
  __syncthreads();

  f32x4 acc[2][4];
  #pragma unroll
  for (int a=0;a<2;a++)
    #pragma unroll
    for (int b=0;b<4;b++) acc[a][b] = (f32x4){0.f,0.f,0.f,0.f};

  const unsigned short* Ab = &As[(32*w + (l & 15))*SA + (l >> 4)*8];
  const unsigned short* Bb = &Ws[(l & 15)*SW + (l >> 4)*8];

  #pragma unroll
  for (int ks = 0; ks < KPAD/32; ++ks){
    short8v a0 = *(const short8v*)(Ab + ks*32);
    short8v a1 = *(const short8v*)(Ab + 16*SA + ks*32);
    short8v b0 = *(const short8v*)(Bb + ks*32);
    short8v b1 = *(const short8v*)(Bb + 16*SW + ks*32);
    short8v b2 = *(const short8v*)(Bb + 32*SW + ks*32);
    short8v b3 = *(const short8v*)(Bb + 48*SW + ks*32);
    acc[0][0] = __builtin_amdgcn_mfma_f32_16x16x32_bf16(a0, b0, acc[0][0], 0, 0, 0);
    acc[0][1] = __builtin_amdgcn_mfma_f32_16x16x32_bf16(a0, b1, acc[0][1], 0, 0, 0);
    acc[0][2] = __builtin_amdgcn_mfma_f32_16x16x32_bf16(a0, b2, acc[0][2], 0, 0, 0);
    acc[0][3] = __builtin_amdgcn_mfma_f32_16x16x32_bf16(a0, b3, acc[0][3], 0, 0, 0);
    acc[1][0] = __builtin_amdgcn_mfma_f32_16x16x32_bf16(a1, b0, acc[1][0], 0, 0, 0);
    acc[1][1] = __builtin_amdgcn_mfma_f32_16x16x32_bf16(a1, b1, acc[1][1], 0, 0, 0);
    acc[1][2] = __builtin_amdgcn_mfma_f32_16x16x32_bf16(a1, b2, acc[1][2], 0, 0, 0);
    acc[1][3] = __builtin_amdgcn_mfma_f32_16x16x32_bf16(a1, b3, acc[1][3], 0, 0, 0);
  }

  if (!POOL){
    #pragma unroll
    for (int rf=0;rf<2;rf++){
      int rbase = r0 + 32*w + 16*rf + 4*(l >> 4);
      #pragma unroll
      for (int cf=0;cf<4;cf++){
        int c = c0 + 16*cf + (l & 15);
        if (c >= ldout) continue;
        float bv = (c < NC) ? bias[c] : 0.f;
        #pragma unroll
        for (int r=0;r<4;r++){
          int rr = rbase + r;
          if (rr < n){
            float v = (c < NC) ? fmaxf(acc[rf][cf][r] + bv, 0.f) : 0.f;
            out[(size_t)rr*ldout + c] = v;
          }
        }
      }
    }
  } else {
    int g0 = batch[r0];
    #pragma unroll
    for (int rf=0;rf<2;rf++){
      int rbase = r0 + 32*w + 16*rf + 4*(l >> 4);
      #pragma unroll
      for (int cf=0;cf<4;cf++){
        int c = c0 + 16*cf + (l & 15);
        if (c >= NC) continue;
        float bv = bias[c];
        int curgi = -1; float m = 0.f;
        #pragma unroll
        for (int r=0;r<4;r++){
          int rr = rbase + r;
          if (rr < n){
            int gi = batch[rr] - g0; if (gi > 1) gi = 1;
            float v = fmaxf(acc[rf][cf][r] + bv, 0.f);
            if (gi != curgi){
              if (curgi >= 0 && m > 0.f) atomicMax(&pmax[curgi][16*cf + (l&15)], __float_as_uint(m));
              curgi = gi; m = v;
            } else m = fmaxf(m, v);
          }
        }
        if (curgi >= 0 && m > 0.f) atomicMax(&pmax[curgi][16*cf + (l&15)], __float_as_uint(m));
      }
    }
    __syncthreads();
    if (tid < 128){
      int gi = tid >> 6, c = tid & 63;
      unsigned v = pmax[gi][c];
      int gg = g0 + gi;
      if (v != 0u && (c0 + c) < NC && gg < G)
        atomicMax(&gpool[(size_t)gg*320 + (c0 + c)], v);
    }
  }
}

// ---------------- f32 64x64 GEMM (head): C = relu(A@W + b) ----------------

__global__ __launch_bounds__(256) void k_gemm64(
    const float* __restrict__ A, int lda,
    const float* __restrict__ W, int NC, int Kreal,
    const float* __restrict__ bias,
    float* __restrict__ Cout, int ldc,
    int n, int Kpad, int relu)
{
  __shared__ float As[64][65];
  __shared__ float Ws[64][68];
  int r0 = blockIdx.x * 64, c0 = blockIdx.y * 64;
  int tid = threadIdx.x;
  int tx = tid & 15, ty = tid >> 4;
  float acc[4][4] = {{0.f,0.f,0.f,0.f},{0.f,0.f,0.f,0.f},{0.f,0.f,0.f,0.f},{0.f,0.f,0.f,0.f}};

  for (int k0 = 0; k0 < Kpad; k0 += 64){
    #pragma unroll
    for (int j=0;j<16;j++){
      int idx = tid + 256*j;
      int r = idx >> 6, kk = idx & 63;
      As[r][kk] = (r0+r < n) ? A[(size_t)(r0+r)*lda + (k0+kk)] : 0.0f;
      Ws[r][kk] = (k0+r < Kreal && c0+kk < NC) ? W[(size_t)(k0+r)*NC + (c0+kk)] : 0.0f;
    }
    __syncthreads();
    #pragma unroll 4
    for (int kk=0; kk<64; ++kk){
      float a0 = As[4*ty+0][kk], a1 = As[4*ty+1][kk], a2 = As[4*ty+2][kk], a3 = As[4*ty+3][kk];
      float4 wv = *(const float4*)&Ws[kk][4*tx];
      acc[0][0] += a0*wv.x; acc[0][1] += a0*wv.y; acc[0][2] += a0*wv.z; acc[0][3] += a0*wv.w;
      acc[1][0] += a1*wv.x; acc[1][1] += a1*wv.y; acc[1][2] += a1*wv.z; acc[1][3] += a1*wv.w;
      acc[2][0] += a2*wv.x; acc[2][1] += a2*wv.y; acc[2][2] += a2*wv.z; acc[2][3] += a2*wv.w;
      acc[3][0] += a3*wv.x; acc[3][1] += a3*wv.y; acc[3][2] += a3*wv.z; acc[3][3] += a3*wv.w;
    }
    __syncthreads();
  }

  #pragma unroll
  for (int u=0;u<4;u++){
    int r = r0 + 4*ty + u;
    if (r < n){
      #pragma unroll
      for (int j=0;j<4;j++){
        int c = c0 + 4*tx + j;
        if (c < NC){
          float v = acc[u][j] + bias[c];
          if (relu) v = fmaxf(v, 0.0f);
          Cout[(size_t)r*ldc + c] = v;
        }
      }
    }
  }
}

// ---------------- final MLP layer ----------------

__global__ __launch_bounds__(256) void k_mlp2(const float* __restrict__ gh, const float* __restrict__ W,
                                              const float* __restrict__ b, float* __restrict__ out){
  __shared__ float s[1024];
  __shared__ float red[256];
  int row = blockIdx.x; int tid = threadIdx.x;
  for (int k = tid; k < 1024; k += 256) s[k] = gh[(size_t)row*1024 + k];
  __syncthreads();
  int c = tid & 127, h = tid >> 7;
  float acc = 0.f;
  for (int k = h*512; k < h*512 + 512; ++k) acc += s[k] * W[(size_t)k*128 + c];
  red[tid] = acc; __syncthreads();
  if (h == 0) out[(size_t)row*128 + c] = red[c] + red[128 + c] + b[c];
}

// ---------------- launcher ----------------

extern "C" void kernel_launch(void* const* d_in, const int* in_sizes, int n_in,
                              void* d_out, int out_size, void* d_ws, size_t ws_size,
                              hipStream_t stream)
{
  const float* x   = (const float*)d_in[0];
  const int*   ei  = (const int*)d_in[1];
  const int*   batch = (const int*)d_in[2];
  const float* W1  = (const float*)d_in[3]; const float* b1  = (const float*)d_in[4];
  const float* W2  = (const float*)d_in[5]; const float* b2  = (const float*)d_in[6];
  const float* W3  = (const float*)d_in[7]; const float* b3  = (const float*)d_in[8];
  const float* Wg1 = (const float*)d_in[9]; const float* bg1 = (const float*)d_in[10];
  const float* Wg2 = (const float*)d_in[11]; const float* bg2 = (const float*)d_in[12];
  float* out = (float*)d_out;

  const int F1 = 75;
  int n = in_sizes[0] / F1;          // 100000
  int E = in_sizes[1] / 2;           // 800000
  int G = out_size / 128;            // 512
  const int* row = ei;
  const int* col = ei + E;

  char* ws = (char*)d_ws;
  size_t off = 0;
  auto alloc = [&](size_t bytes){ size_t o = off; off += (bytes + 255) & ~(size_t)255; return o; };
  float* xp    = (float*)(ws + alloc((size_t)n*80*4));   // padded x; aliased as bufH1 after prop1
  float* bufQ  = (float*)(ws + alloc((size_t)n*160*4));
  float* bufH2 = (float*)(ws + alloc((size_t)n*160*4));
  float* dinv  = (float*)(ws + alloc((size_t)n*4));
  int*   indeg = (int*)  (ws + alloc((size_t)n*4));
  int*   rp    = (int*)  (ws + alloc((size_t)(n+1)*4));
  int*   nxt   = (int*)  (ws + alloc((size_t)n*4));
  int*   csr   = (int*)  (ws + alloc((size_t)E*4));
  int*   bsums = (int*)  (ws + alloc(1024*4));
  unsigned* g  = (unsigned*)(ws + alloc((size_t)G*320*4));
  float* gh    = (float*)(ws + alloc((size_t)G*1024*4));
  unsigned short* Wt1 = (unsigned short*)(ws + alloc((size_t)128*96*2));
  unsigned short* Wt2 = (unsigned short*)(ws + alloc((size_t)192*96*2));
  unsigned short* Wt3 = (unsigned short*)(ws + alloc((size_t)320*160*2));
  float* bufH1 = xp;

  hipMemsetAsync(indeg, 0, (size_t)n*4, stream);
  hipMemsetAsync(g, 0, (size_t)G*320*4, stream);

  k_deg<<<(E+255)/256, 256, 0, stream>>>(col, indeg, E);
  k_dinv<<<(n+255)/256, 256, 0, stream>>>(indeg, dinv, n);

  int nb = (n + 1023) / 1024;
  k_scan1<<<nb, 256, 0, stream>>>(indeg, rp, bsums, n);
  k_scan2<<<1, 128, 0, stream>>>(bsums, rp, nb, n);
  k_scan3<<<(n+255)/256, 256, 0, stream>>>(rp, nxt, bsums, n);
  k_scatter<<<(E+255)/256, 256, 0, stream>>>(row, col, nxt, csr, E);

  k_pad<<<4096, 256, 0, stream>>>(x, xp, n);
  k_wt<<<(128*96+255)/256, 256, 0, stream>>>(W1, Wt1, 75, 75, 96, 128);
  k_wt<<<(192*96+255)/256, 256, 0, stream>>>(W2, Wt2, 75, 150, 96, 192);
  k_wt<<<(320*160+255)/256, 256, 0, stream>>>(W3, Wt3, 150, 300, 160, 320);

  int pb = (n + 3) / 4;
  int mb = (n + 127) / 128;   // 782

  // layer 1
  k_prop<80><<<pb, 256, 0, stream>>>(xp, dinv, rp, csr, bufQ, n);
  {
    dim3 grid(mb, 2);
    k_gemm_mfma<96,80,0><<<grid, 256, 0, stream>>>(bufQ, Wt1, b1, bufH1, 80, 75,
                                                   nullptr, nullptr, n, G);
  }
  // layer 2
  k_prop<80><<<pb, 256, 0, stream>>>(bufH1, dinv, rp, csr, bufQ, n);
  {
    dim3 grid(mb, 3);
    k_gemm_mfma<96,80,0><<<grid, 256, 0, stream>>>(bufQ, Wt2, b2, bufH2, 160, 150,
                                                   nullptr, nullptr, n, G);
  }
  // layer 3 + fused relu + segment-max pool -> g (f32 bits via atomicMax, stride 320)
  k_prop<160><<<pb, 256, 0, stream>>>(bufH2, dinv, rp, csr, bufQ, n);
  {
    dim3 grid(mb, 5);
    k_gemm_mfma<160,160,1><<<grid, 256, 0, stream>>>(bufQ, Wt3, b3, nullptr, 0, 300,
                                                     batch, g, n, G);
  }
  // head: gh = relu(g @ Wg1 + bg1)  [f32]
  {
    dim3 grid((G+63)/64, 16);
    k_gemm64<<<grid, 256, 0, stream>>>((const float*)g, 320, Wg1, 1024, 300, bg1, gh, 1024,
                                       G, 320, 1);
  }
  k_mlp2<<<G, 256, 0, stream>>>(gh, Wg2, bg2, out);
}

// Round 5
// 641.644 us; speedup vs baseline: 2.1493x; 1.2929x over previous
//
#include <hip/hip_runtime.h>

typedef __attribute__((ext_vector_type(8))) short short8v;   // 8 bf16
typedef __attribute__((ext_vector_type(4))) float f32x4;

__device__ inline unsigned short f2bf(float x){
  union{float f; unsigned u;} v; v.f = x;
  unsigned r = (v.u + 0x7FFFu + ((v.u >> 16) & 1u)) >> 16;
  return (unsigned short)r;
}

// ---------------- preprocessing kernels ----------------

__global__ void k_deg(const int* __restrict__ col, int* __restrict__ indeg, int E){
  int e = blockIdx.x*blockDim.x + threadIdx.x;
  if (e < E) atomicAdd(&indeg[col[e]], 1);
}

__global__ void k_dinv(const int* __restrict__ indeg, float* __restrict__ dinv, int n){
  int i = blockIdx.x*blockDim.x + threadIdx.x;
  if (i < n) dinv[i] = rsqrtf((float)(indeg[i] + 1));
}

__global__ __launch_bounds__(256) void k_scan1(const int* __restrict__ indeg, int* __restrict__ rp,
                                               int* __restrict__ bsums, int n){
  __shared__ int s[256];
  int b = blockIdx.x, t = threadIdx.x;
  int base = b*1024 + t*4;
  int v[4]; int tsum = 0;
  #pragma unroll
  for (int j=0;j<4;j++){ v[j] = (base+j < n) ? indeg[base+j] : 0; tsum += v[j]; }
  s[t] = tsum; __syncthreads();
  for (int d=1; d<256; d<<=1){ int x = (t>=d) ? s[t-d] : 0; __syncthreads(); s[t] += x; __syncthreads(); }
  int run = s[t] - tsum;
  if (t == 255) bsums[b] = s[255];
  #pragma unroll
  for (int j=0;j<4;j++){ if (base+j < n){ rp[base+j] = run; } run += v[j]; }
}

__global__ __launch_bounds__(128) void k_scan2(int* bsums, int* rp, int nb, int n){
  __shared__ int s[128];
  int t = threadIdx.x;
  int orig = (t < nb) ? bsums[t] : 0;
  s[t] = orig; __syncthreads();
  for (int d=1; d<128; d<<=1){ int x = (t>=d) ? s[t-d] : 0; __syncthreads(); s[t] += x; __syncthreads(); }
  if (t < nb) bsums[t] = s[t] - orig;
  if (t == 127) rp[n] = s[127];
}

__global__ void k_scan3(int* __restrict__ rp, int* __restrict__ nxt, const int* __restrict__ bsums, int n){
  int i = blockIdx.x*blockDim.x + threadIdx.x;
  if (i < n){ int v = rp[i] + bsums[i >> 10]; rp[i] = v; nxt[i] = v; }
}

__global__ void k_scatter(const int* __restrict__ row, const int* __restrict__ col,
                          int* __restrict__ nxt, int* __restrict__ csr, int E){
  int e = blockIdx.x*blockDim.x + threadIdx.x;
  if (e < E){ int c = col[e]; int p = atomicAdd(&nxt[c], 1); csr[p] = row[e]; }
}

// x restage: 75-wide -> 80-stride zero-padded
__global__ void k_pad(const float* __restrict__ x, float* __restrict__ xp, int n){
  long total = (long)n * 80;
  for (long idx = blockIdx.x*(long)blockDim.x + threadIdx.x; idx < total; idx += (long)gridDim.x*blockDim.x){
    int r = (int)(idx / 80), f = (int)(idx % 80);
    xp[idx] = (f < 75) ? x[(size_t)r*75 + f] : 0.0f;
  }
}

// W (f32, Kreal x NC) -> Wt (bf16, NCP x KPAD, transposed, zero-padded)
__global__ void k_wt(const float* __restrict__ W, unsigned short* __restrict__ Wt,
                     int Kreal, int NC, int KPAD, int NCP){
  int idx = blockIdx.x*blockDim.x + threadIdx.x;
  if (idx >= NCP*KPAD) return;
  int c = idx / KPAD, k = idx % KPAD;
  float v = (c < NC && k < Kreal) ? W[(size_t)k*NC + c] : 0.0f;
  Wt[idx] = f2bf(v);
}

// ---------------- sparse propagation: out = D^-1/2 (A+I) D^-1/2 h ----------------
// thread = (node-slot, feature-chunk): all lanes carry a productive float4 gather.

template<int FP>
__global__ __launch_bounds__(256) void k_prop(const float* __restrict__ h, const float* __restrict__ dinv,
                                              const int* __restrict__ rp, const int* __restrict__ csr,
                                              float* __restrict__ out, int n){
  constexpr int TPN = FP/4;         // threads per node
  constexpr int NPB = 256/TPN;      // nodes per block
  int q = threadIdx.x / TPN;
  int t = threadIdx.x - q*TPN;
  if (q >= NPB) return;
  int node = blockIdx.x*NPB + q;
  if (node >= n) return;
  int f = 4*t;
  float di = dinv[node];
  float4 acc;
  {
    float4 v = *(const float4*)&h[(size_t)node*FP + f];
    acc.x = di*v.x; acc.y = di*v.y; acc.z = di*v.z; acc.w = di*v.w;
  }
  int e0 = rp[node], e1 = rp[node+1];
  int e = e0;
  for (; e + 4 <= e1; e += 4){
    int s0 = csr[e], s1 = csr[e+1], s2 = csr[e+2], s3 = csr[e+3];
    float d0 = dinv[s0], d1 = dinv[s1], d2 = dinv[s2], d3 = dinv[s3];
    float4 v0 = *(const float4*)&h[(size_t)s0*FP + f];
    float4 v1 = *(const float4*)&h[(size_t)s1*FP + f];
    float4 v2 = *(const float4*)&h[(size_t)s2*FP + f];
    float4 v3 = *(const float4*)&h[(size_t)s3*FP + f];
    acc.x += d0*v0.x + d1*v1.x + d2*v2.x + d3*v3.x;
    acc.y += d0*v0.y + d1*v1.y + d2*v2.y + d3*v3.y;
    acc.z += d0*v0.z + d1*v1.z + d2*v2.z + d3*v3.z;
    acc.w += d0*v0.w + d1*v1.w + d2*v2.w + d3*v3.w;
  }
  for (; e < e1; ++e){
    int s = csr[e]; float ds = dinv[s];
    float4 v = *(const float4*)&h[(size_t)s*FP + f];
    acc.x += ds*v.x; acc.y += ds*v.y; acc.z += ds*v.z; acc.w += ds*v.w;
  }
  float4 o; o.x = di*acc.x; o.y = di*acc.y; o.z = di*acc.z; o.w = di*acc.w;
  *(float4*)&out[(size_t)node*FP + f] = o;
}

// ---------------- bf16 MFMA GEMM (whole-K in LDS): out = relu(A@W+b), optional fused pool ----------------
// BM=128 x BN=64, 256 threads (4 waves).

template<int KPAD, int KG, int POOL>
__global__ __launch_bounds__(256) void k_gemm_mfma(
    const float* __restrict__ A, const unsigned short* __restrict__ Wt,
    const float* __restrict__ bias,
    float* __restrict__ out, int ldout, int NC,
    const int* __restrict__ batch, unsigned* __restrict__ gpool,
    int n, int G)
{
  constexpr int SA = KPAD + 8;
  constexpr int SW = KPAD + 8;
  __shared__ unsigned short As[128*SA];
  __shared__ unsigned short Ws[64*SW];
  __shared__ unsigned pmax[2][64];

  int tid = threadIdx.x;
  int r0 = blockIdx.x * 128, c0 = blockIdx.y * 64;
  int w = tid >> 6, l = tid & 63;

  {
    constexpr int C4 = KPAD/4;
    #pragma unroll
    for (int i = 0; i < 128*C4/256; ++i){
      int idx = tid + 256*i;
      int r = idx / C4, c4 = idx % C4;
      float4 v = make_float4(0.f,0.f,0.f,0.f);
      if (r0 + r < n && 4*c4 < KG) v = *(const float4*)&A[(size_t)(r0+r)*KG + 4*c4];
      unsigned p01 = (unsigned)f2bf(v.x) | ((unsigned)f2bf(v.y) << 16);
      unsigned p23 = (unsigned)f2bf(v.z) | ((unsigned)f2bf(v.w) << 16);
      *(uint2*)&As[r*SA + 4*c4] = make_uint2(p01, p23);
    }
  }
  {
    constexpr int K8 = KPAD/8;
    #pragma unroll
    for (int i = 0; i < 64*K8/256; ++i){
      int idx = tid + 256*i;
      int wr = idx / K8, wk = idx % K8;
      short8v wv = *(const short8v*)&Wt[(size_t)(c0+wr)*KPAD + 8*wk];
      *(short8v*)&Ws[wr*SW + 8*wk] = wv;
    }
  }
  if (POOL){ if (tid < 128) pmax[tid>>6][tid&63] = 0u; }
  __syncthreads();

  f32x4 acc[2][4];
  #pragma unroll
  for (int a=0;a<2;a++)
    #pragma unroll
    for (int b=0;b<4;b++) acc[a][b] = (f32x4){0.f,0.f,0.f,0.f};

  const unsigned short* Ab = &As[(32*w + (l & 15))*SA + (l >> 4)*8];
  const unsigned short* Bb = &Ws[(l & 15)*SW + (l >> 4)*8];

  #pragma unroll
  for (int ks = 0; ks < KPAD/32; ++ks){
    short8v a0 = *(const short8v*)(Ab + ks*32);
    short8v a1 = *(const short8v*)(Ab + 16*SA + ks*32);
    short8v b0 = *(const short8v*)(Bb + ks*32);
    short8v b1 = *(const short8v*)(Bb + 16*SW + ks*32);
    short8v b2 = *(const short8v*)(Bb + 32*SW + ks*32);
    short8v b3 = *(const short8v*)(Bb + 48*SW + ks*32);
    acc[0][0] = __builtin_amdgcn_mfma_f32_16x16x32_bf16(a0, b0, acc[0][0], 0, 0, 0);
    acc[0][1] = __builtin_amdgcn_mfma_f32_16x16x32_bf16(a0, b1, acc[0][1], 0, 0, 0);
    acc[0][2] = __builtin_amdgcn_mfma_f32_16x16x32_bf16(a0, b2, acc[0][2], 0, 0, 0);
    acc[0][3] = __builtin_amdgcn_mfma_f32_16x16x32_bf16(a0, b3, acc[0][3], 0, 0, 0);
    acc[1][0] = __builtin_amdgcn_mfma_f32_16x16x32_bf16(a1, b0, acc[1][0], 0, 0, 0);
    acc[1][1] = __builtin_amdgcn_mfma_f32_16x16x32_bf16(a1, b1, acc[1][1], 0, 0, 0);
    acc[1][2] = __builtin_amdgcn_mfma_f32_16x16x32_bf16(a1, b2, acc[1][2], 0, 0, 0);
    acc[1][3] = __builtin_amdgcn_mfma_f32_16x16x32_bf16(a1, b3, acc[1][3], 0, 0, 0);
  }

  if (!POOL){
    #pragma unroll
    for (int rf=0;rf<2;rf++){
      int rbase = r0 + 32*w + 16*rf + 4*(l >> 4);
      #pragma unroll
      for (int cf=0;cf<4;cf++){
        int c = c0 + 16*cf + (l & 15);
        if (c >= ldout) continue;
        float bv = (c < NC) ? bias[c] : 0.f;
        #pragma unroll
        for (int r=0;r<4;r++){
          int rr = rbase + r;
          if (rr < n){
            float v = (c < NC) ? fmaxf(acc[rf][cf][r] + bv, 0.f) : 0.f;
            out[(size_t)rr*ldout + c] = v;
          }
        }
      }
    }
  } else {
    int g0 = batch[r0];
    #pragma unroll
    for (int rf=0;rf<2;rf++){
      int rbase = r0 + 32*w + 16*rf + 4*(l >> 4);
      #pragma unroll
      for (int cf=0;cf<4;cf++){
        int c = c0 + 16*cf + (l & 15);
        if (c >= NC) continue;
        float bv = bias[c];
        int curgi = -1; float m = 0.f;
        #pragma unroll
        for (int r=0;r<4;r++){
          int rr = rbase + r;
          if (rr < n){
            int gi = batch[rr] - g0; if (gi > 1) gi = 1;
            float v = fmaxf(acc[rf][cf][r] + bv, 0.f);
            if (gi != curgi){
              if (curgi >= 0 && m > 0.f) atomicMax(&pmax[curgi][16*cf + (l&15)], __float_as_uint(m));
              curgi = gi; m = v;
            } else m = fmaxf(m, v);
          }
        }
        if (curgi >= 0 && m > 0.f) atomicMax(&pmax[curgi][16*cf + (l&15)], __float_as_uint(m));
      }
    }
    __syncthreads();
    if (tid < 128){
      int gi = tid >> 6, c = tid & 63;
      unsigned v = pmax[gi][c];
      int gg = g0 + gi;
      if (v != 0u && (c0 + c) < NC && gg < G)
        atomicMax(&gpool[(size_t)gg*320 + (c0 + c)], v);
    }
  }
}

// ---------------- bf16 MFMA GEMM with BK=64 K-loop (head layers) ----------------
// BM=128 x BN=64, 256 threads. A: f32 [n][lda]; Wt: bf16 [NCP][ldw] transposed.

__global__ __launch_bounds__(256) void k_gemm_kloop(
    const float* __restrict__ A, int lda, int Ktot,
    const unsigned short* __restrict__ Wt, int ldw,
    const float* __restrict__ bias,
    float* __restrict__ out, int ldout, int NC,
    int n, int relu)
{
  constexpr int SA = 72, SW = 72;
  __shared__ unsigned short As[128*SA];
  __shared__ unsigned short Ws[64*SW];
  int tid = threadIdx.x;
  int r0 = blockIdx.x * 128, c0 = blockIdx.y * 64;
  int w = tid >> 6, l = tid & 63;

  f32x4 acc[2][4];
  #pragma unroll
  for (int a=0;a<2;a++)
    #pragma unroll
    for (int b=0;b<4;b++) acc[a][b] = (f32x4){0.f,0.f,0.f,0.f};

  const unsigned short* Ab = &As[(32*w + (l & 15))*SA + (l >> 4)*8];
  const unsigned short* Bb = &Ws[(l & 15)*SW + (l >> 4)*8];

  for (int k0 = 0; k0 < Ktot; k0 += 64){
    #pragma unroll
    for (int i=0;i<8;i++){
      int idx = tid + 256*i;
      int r = idx >> 4, c4 = idx & 15;
      float4 v = make_float4(0.f,0.f,0.f,0.f);
      if (r0 + r < n) v = *(const float4*)&A[(size_t)(r0+r)*lda + k0 + 4*c4];
      unsigned p01 = (unsigned)f2bf(v.x) | ((unsigned)f2bf(v.y) << 16);
      unsigned p23 = (unsigned)f2bf(v.z) | ((unsigned)f2bf(v.w) << 16);
      *(uint2*)&As[r*SA + 4*c4] = make_uint2(p01, p23);
    }
    #pragma unroll
    for (int i=0;i<2;i++){
      int idx = tid + 256*i;
      int wr = idx >> 3, wk = idx & 7;
      short8v wv = *(const short8v*)&Wt[(size_t)(c0+wr)*ldw + k0 + 8*wk];
      *(short8v*)&Ws[wr*SW + 8*wk] = wv;
    }
    __syncthreads();
    #pragma unroll
    for (int ks = 0; ks < 2; ++ks){
      short8v a0 = *(const short8v*)(Ab + ks*32);
      short8v a1 = *(const short8v*)(Ab + 16*SA + ks*32);
      short8v b0 = *(const short8v*)(Bb + ks*32);
      short8v b1 = *(const short8v*)(Bb + 16*SW + ks*32);
      short8v b2 = *(const short8v*)(Bb + 32*SW + ks*32);
      short8v b3 = *(const short8v*)(Bb + 48*SW + ks*32);
      acc[0][0] = __builtin_amdgcn_mfma_f32_16x16x32_bf16(a0, b0, acc[0][0], 0, 0, 0);
      acc[0][1] = __builtin_amdgcn_mfma_f32_16x16x32_bf16(a0, b1, acc[0][1], 0, 0, 0);
      acc[0][2] = __builtin_amdgcn_mfma_f32_16x16x32_bf16(a0, b2, acc[0][2], 0, 0, 0);
      acc[0][3] = __builtin_amdgcn_mfma_f32_16x16x32_bf16(a0, b3, acc[0][3], 0, 0, 0);
      acc[1][0] = __builtin_amdgcn_mfma_f32_16x16x32_bf16(a1, b0, acc[1][0], 0, 0, 0);
      acc[1][1] = __builtin_amdgcn_mfma_f32_16x16x32_bf16(a1, b1, acc[1][1], 0, 0, 0);
      acc[1][2] = __builtin_amdgcn_mfma_f32_16x16x32_bf16(a1, b2, acc[1][2], 0, 0, 0);
      acc[1][3] = __builtin_amdgcn_mfma_f32_16x16x32_bf16(a1, b3, acc[1][3], 0, 0, 0);
    }
    __syncthreads();
  }

  #pragma unroll
  for (int rf=0;rf<2;rf++){
    int rbase = r0 + 32*w + 16*rf + 4*(l >> 4);
    #pragma unroll
    for (int cf=0;cf<4;cf++){
      int c = c0 + 16*cf + (l & 15);
      if (c >= NC) continue;
      float bv = bias[c];
      #pragma unroll
      for (int r=0;r<4;r++){
        int rr = rbase + r;
        if (rr < n){
          float v = acc[rf][cf][r] + bv;
          if (relu) v = fmaxf(v, 0.f);
          out[(size_t)rr*ldout + c] = v;
        }
      }
    }
  }
}

// ---------------- launcher ----------------

extern "C" void kernel_launch(void* const* d_in, const int* in_sizes, int n_in,
                              void* d_out, int out_size, void* d_ws, size_t ws_size,
                              hipStream_t stream)
{
  const float* x   = (const float*)d_in[0];
  const int*   ei  = (const int*)d_in[1];
  const int*   batch = (const int*)d_in[2];
  const float* W1  = (const float*)d_in[3]; const float* b1  = (const float*)d_in[4];
  const float* W2  = (const float*)d_in[5]; const float* b2  = (const float*)d_in[6];
  const float* W3  = (const float*)d_in[7]; const float* b3  = (const float*)d_in[8];
  const float* Wg1 = (const float*)d_in[9]; const float* bg1 = (const float*)d_in[10];
  const float* Wg2 = (const float*)d_in[11]; const float* bg2 = (const float*)d_in[12];
  float* out = (float*)d_out;

  const int F1 = 75;
  int n = in_sizes[0] / F1;          // 100000
  int E = in_sizes[1] / 2;           // 800000
  int G = out_size / 128;            // 512
  const int* row = ei;
  const int* col = ei + E;

  char* ws = (char*)d_ws;
  size_t off = 0;
  auto alloc = [&](size_t bytes){ size_t o = off; off += (bytes + 255) & ~(size_t)255; return o; };
  float* xp    = (float*)(ws + alloc((size_t)n*80*4));   // padded x; aliased as bufH1 after prop1
  float* bufQ  = (float*)(ws + alloc((size_t)n*160*4));
  float* bufH2 = (float*)(ws + alloc((size_t)n*160*4));
  float* dinv  = (float*)(ws + alloc((size_t)n*4));
  int*   indeg = (int*)  (ws + alloc((size_t)n*4));
  int*   rp    = (int*)  (ws + alloc((size_t)(n+1)*4));
  int*   nxt   = (int*)  (ws + alloc((size_t)n*4));
  int*   csr   = (int*)  (ws + alloc((size_t)E*4));
  int*   bsums = (int*)  (ws + alloc(1024*4));
  unsigned* g  = (unsigned*)(ws + alloc((size_t)G*320*4));
  float* gh    = (float*)(ws + alloc((size_t)G*1024*4));
  unsigned short* Wt1  = (unsigned short*)(ws + alloc((size_t)128*96*2));
  unsigned short* Wt2  = (unsigned short*)(ws + alloc((size_t)192*96*2));
  unsigned short* Wt3  = (unsigned short*)(ws + alloc((size_t)320*160*2));
  unsigned short* Wg1t = (unsigned short*)(ws + alloc((size_t)1024*320*2));
  unsigned short* Wg2t = (unsigned short*)(ws + alloc((size_t)128*1024*2));
  float* bufH1 = xp;

  hipMemsetAsync(indeg, 0, (size_t)n*4, stream);
  hipMemsetAsync(g, 0, (size_t)G*320*4, stream);

  k_deg<<<(E+255)/256, 256, 0, stream>>>(col, indeg, E);
  k_dinv<<<(n+255)/256, 256, 0, stream>>>(indeg, dinv, n);

  int nb = (n + 1023) / 1024;
  k_scan1<<<nb, 256, 0, stream>>>(indeg, rp, bsums, n);
  k_scan2<<<1, 128, 0, stream>>>(bsums, rp, nb, n);
  k_scan3<<<(n+255)/256, 256, 0, stream>>>(rp, nxt, bsums, n);
  k_scatter<<<(E+255)/256, 256, 0, stream>>>(row, col, nxt, csr, E);

  k_pad<<<4096, 256, 0, stream>>>(x, xp, n);
  k_wt<<<(128*96+255)/256, 256, 0, stream>>>(W1, Wt1, 75, 75, 96, 128);
  k_wt<<<(192*96+255)/256, 256, 0, stream>>>(W2, Wt2, 75, 150, 96, 192);
  k_wt<<<(320*160+255)/256, 256, 0, stream>>>(W3, Wt3, 150, 300, 160, 320);
  k_wt<<<(1024*320+255)/256, 256, 0, stream>>>(Wg1, Wg1t, 300, 1024, 320, 1024);
  k_wt<<<(128*1024+255)/256, 256, 0, stream>>>(Wg2, Wg2t, 1024, 128, 1024, 128);

  int mb = (n + 127) / 128;   // 782

  // layer 1
  k_prop<80><<<(n+11)/12, 256, 0, stream>>>(xp, dinv, rp, csr, bufQ, n);
  {
    dim3 grid(mb, 2);
    k_gemm_mfma<96,80,0><<<grid, 256, 0, stream>>>(bufQ, Wt1, b1, bufH1, 80, 75,
                                                   nullptr, nullptr, n, G);
  }
  // layer 2
  k_prop<80><<<(n+11)/12, 256, 0, stream>>>(bufH1, dinv, rp, csr, bufQ, n);
  {
    dim3 grid(mb, 3);
    k_gemm_mfma<96,80,0><<<grid, 256, 0, stream>>>(bufQ, Wt2, b2, bufH2, 160, 150,
                                                   nullptr, nullptr, n, G);
  }
  // layer 3 + fused relu + segment-max pool -> g (stride 320)
  k_prop<160><<<(n+5)/6, 256, 0, stream>>>(bufH2, dinv, rp, csr, bufQ, n);
  {
    dim3 grid(mb, 5);
    k_gemm_mfma<160,160,1><<<grid, 256, 0, stream>>>(bufQ, Wt3, b3, nullptr, 0, 300,
                                                     batch, g, n, G);
  }
  // head 1: gh = relu(g @ Wg1 + bg1)   [MFMA, K=320]
  {
    dim3 grid(G/128, 1024/64);
    k_gemm_kloop<<<grid, 256, 0, stream>>>((const float*)g, 320, 320, Wg1t, 320, bg1,
                                           gh, 1024, 1024, G, 1);
  }
  // head 2: out = gh @ Wg2 + bg2   [MFMA, K=1024]
  {
    dim3 grid(G/128, 128/64);
    k_gemm_kloop<<<grid, 256, 0, stream>>>(gh, 1024, 1024, Wg2t, 1024, bg2,
                                           out, 128, 128, G, 0);
  }
}

// Round 6
// 497.293 us; speedup vs baseline: 2.7732x; 1.2903x over previous
//
#include <hip/hip_runtime.h>

typedef __attribute__((ext_vector_type(8))) short short8v;   // 8 bf16
typedef __attribute__((ext_vector_type(4))) float f32x4;
typedef unsigned short u16;

__device__ inline u16 f2bf(float x){
  union{float f; unsigned u;} v; v.f = x;
  unsigned r = (v.u + 0x7FFFu + ((v.u >> 16) & 1u)) >> 16;
  return (u16)r;
}
__device__ inline float b2f(u16 u){
  union{unsigned u32; float f;} w; w.u32 = (unsigned)u << 16; return w.f;
}

// ---------------- preprocessing kernels ----------------

__global__ void k_deg(const int* __restrict__ col, int* __restrict__ indeg, int E){
  int e = blockIdx.x*blockDim.x + threadIdx.x;
  if (e < E) atomicAdd(&indeg[col[e]], 1);
}

__global__ void k_dinv(const int* __restrict__ indeg, float* __restrict__ dinv, int n){
  int i = blockIdx.x*blockDim.x + threadIdx.x;
  if (i < n) dinv[i] = rsqrtf((float)(indeg[i] + 1));
}

__global__ __launch_bounds__(256) void k_scan1(const int* __restrict__ indeg, int* __restrict__ rp,
                                               int* __restrict__ bsums, int n){
  __shared__ int s[256];
  int b = blockIdx.x, t = threadIdx.x;
  int base = b*1024 + t*4;
  int v[4]; int tsum = 0;
  #pragma unroll
  for (int j=0;j<4;j++){ v[j] = (base+j < n) ? indeg[base+j] : 0; tsum += v[j]; }
  s[t] = tsum; __syncthreads();
  for (int d=1; d<256; d<<=1){ int x = (t>=d) ? s[t-d] : 0; __syncthreads(); s[t] += x; __syncthreads(); }
  int run = s[t] - tsum;
  if (t == 255) bsums[b] = s[255];
  #pragma unroll
  for (int j=0;j<4;j++){ if (base+j < n){ rp[base+j] = run; } run += v[j]; }
}

__global__ __launch_bounds__(128) void k_scan2(int* bsums, int* rp, int nb, int n){
  __shared__ int s[128];
  int t = threadIdx.x;
  int orig = (t < nb) ? bsums[t] : 0;
  s[t] = orig; __syncthreads();
  for (int d=1; d<128; d<<=1){ int x = (t>=d) ? s[t-d] : 0; __syncthreads(); s[t] += x; __syncthreads(); }
  if (t < nb) bsums[t] = s[t] - orig;
  if (t == 127) rp[n] = s[127];
}

__global__ void k_scan3(int* __restrict__ rp, int* __restrict__ nxt, const int* __restrict__ bsums, int n){
  int i = blockIdx.x*blockDim.x + threadIdx.x;
  if (i < n){ int v = rp[i] + bsums[i >> 10]; rp[i] = v; nxt[i] = v; }
}

__global__ void k_scatter(const int* __restrict__ row, const int* __restrict__ col,
                          int* __restrict__ nxt, int* __restrict__ csr, int E){
  int e = blockIdx.x*blockDim.x + threadIdx.x;
  if (e < E){ int c = col[e]; int p = atomicAdd(&nxt[c], 1); csr[p] = row[e]; }
}

// x f32 [n][75] -> xb bf16 [n][80] zero-padded
__global__ void k_padb(const float* __restrict__ x, u16* __restrict__ xb, int n){
  long total = (long)n*80;
  for (long idx = blockIdx.x*(long)blockDim.x + threadIdx.x; idx < total; idx += (long)gridDim.x*blockDim.x){
    int r = (int)(idx/80), fcol = (int)(idx%80);
    xb[idx] = f2bf(fcol < 75 ? x[(size_t)r*75 + fcol] : 0.f);
  }
}

// W (f32, Kreal x NC) -> Wt (bf16, NCP x KPAD, transposed, zero-padded)
__global__ void k_wt(const float* __restrict__ W, u16* __restrict__ Wt,
                     int Kreal, int NC, int KPAD, int NCP){
  int idx = blockIdx.x*blockDim.x + threadIdx.x;
  if (idx >= NCP*KPAD) return;
  int c = idx / KPAD, k = idx % KPAD;
  float v = (c < NC && k < Kreal) ? W[(size_t)k*NC + c] : 0.0f;
  Wt[idx] = f2bf(v);
}

// ---------------- sparse propagation (bf16 features): out = D^-1/2 (A+I) D^-1/2 h ----------------
// thread = (node-slot, 8-feature chunk): every lane does one 16B gather per edge.

template<int FP>   // bf16 row width, multiple of 8
__global__ __launch_bounds__(256) void k_prop_bf(const u16* __restrict__ h, const float* __restrict__ dinv,
                                                 const int* __restrict__ rp, const int* __restrict__ csr,
                                                 u16* __restrict__ out, int n){
  constexpr int TPN = FP/8;
  constexpr int NPB = 256/TPN;
  int q = threadIdx.x / TPN;
  int t = threadIdx.x - q*TPN;
  if (q >= NPB) return;
  int node = blockIdx.x*NPB + q;
  if (node >= n) return;
  int f = 8*t;
  float di = dinv[node];
  float acc[8];
  {
    short8v v = *(const short8v*)&h[(size_t)node*FP + f];
    #pragma unroll
    for (int i=0;i<8;i++) acc[i] = di*b2f((u16)v[i]);
  }
  int e0 = rp[node], e1 = rp[node+1];
  int e = e0;
  for (; e + 4 <= e1; e += 4){
    int s0 = csr[e], s1 = csr[e+1], s2 = csr[e+2], s3 = csr[e+3];
    float d0 = dinv[s0], d1 = dinv[s1], d2 = dinv[s2], d3 = dinv[s3];
    short8v v0 = *(const short8v*)&h[(size_t)s0*FP + f];
    short8v v1 = *(const short8v*)&h[(size_t)s1*FP + f];
    short8v v2 = *(const short8v*)&h[(size_t)s2*FP + f];
    short8v v3 = *(const short8v*)&h[(size_t)s3*FP + f];
    #pragma unroll
    for (int i=0;i<8;i++)
      acc[i] += d0*b2f((u16)v0[i]) + d1*b2f((u16)v1[i]) + d2*b2f((u16)v2[i]) + d3*b2f((u16)v3[i]);
  }
  for (; e < e1; ++e){
    int s = csr[e]; float ds = dinv[s];
    short8v v = *(const short8v*)&h[(size_t)s*FP + f];
    #pragma unroll
    for (int i=0;i<8;i++) acc[i] += ds*b2f((u16)v[i]);
  }
  short8v o;
  #pragma unroll
  for (int i=0;i<8;i++) o[i] = (short)f2bf(di*acc[i]);
  *(short8v*)&out[(size_t)node*FP + f] = o;
}

// ---------------- bf16 MFMA GEMM, column-loop (A staged ONCE): out = relu(A@W+b) ----------------
// BM=128, 256 threads (4 waves). A: bf16 [n][LDA]. Wt: bf16 [NT*64][KPAD]. Per col-tile: 64 cols.

template<int KPAD, int LDA, int POOL>
__global__ __launch_bounds__(256) void k_gemm_bf(
    const u16* __restrict__ A, const u16* __restrict__ Wt,
    const float* __restrict__ bias,
    u16* __restrict__ out, int ldout, int NC, int NT,
    const int* __restrict__ batch, unsigned* __restrict__ gpool, int ldg,
    int n, int G)
{
  constexpr int SA = KPAD + 8;
  constexpr int SW = KPAD + 8;
  constexpr int C8 = KPAD/8;
  constexpr int R8 = LDA/8;
  __shared__ u16 As[128*SA];
  __shared__ u16 Ws[64*SW];
  __shared__ unsigned pmax[2][64];

  int tid = threadIdx.x;
  int r0 = blockIdx.x * 128;
  int w = tid >> 6, l = tid & 63;

  // stage A once: 128 x KPAD (bf16 direct, zero-fill beyond LDA)
  #pragma unroll
  for (int i = 0; i < 128*C8/256; ++i){
    int idx = tid + 256*i;
    int r = idx / C8, c8 = idx % C8;
    short8v v = (short8v){0,0,0,0,0,0,0,0};
    if (r0 + r < n && c8 < R8) v = *(const short8v*)&A[(size_t)(r0+r)*LDA + 8*c8];
    *(short8v*)&As[r*SA + 8*c8] = v;
  }

  const u16* Ab = &As[(32*w + (l & 15))*SA + (l >> 4)*8];
  const u16* Bb = &Ws[(l & 15)*SW + (l >> 4)*8];

  for (int ct = 0; ct < NT; ++ct){
    if (ct) __syncthreads();          // prior tile done reading Ws/pmax
    // stage W tile: 64 x KPAD
    #pragma unroll
    for (int i = 0; i < 64*C8/256; ++i){
      int idx = tid + 256*i;
      int wr = idx / C8, wk = idx % C8;
      *(short8v*)&Ws[wr*SW + 8*wk] = *(const short8v*)&Wt[(size_t)(ct*64 + wr)*KPAD + 8*wk];
    }
    if (POOL){ if (tid < 128) pmax[tid>>6][tid&63] = 0u; }
    __syncthreads();                  // W (and A on ct==0) visible

    f32x4 acc[2][4];
    #pragma unroll
    for (int a=0;a<2;a++)
      #pragma unroll
      for (int b=0;b<4;b++) acc[a][b] = (f32x4){0.f,0.f,0.f,0.f};

    #pragma unroll
    for (int ks = 0; ks < KPAD/32; ++ks){
      short8v a0 = *(const short8v*)(Ab + ks*32);
      short8v a1 = *(const short8v*)(Ab + 16*SA + ks*32);
      short8v b0 = *(const short8v*)(Bb + ks*32);
      short8v b1 = *(const short8v*)(Bb + 16*SW + ks*32);
      short8v b2 = *(const short8v*)(Bb + 32*SW + ks*32);
      short8v b3 = *(const short8v*)(Bb + 48*SW + ks*32);
      acc[0][0] = __builtin_amdgcn_mfma_f32_16x16x32_bf16(a0, b0, acc[0][0], 0, 0, 0);
      acc[0][1] = __builtin_amdgcn_mfma_f32_16x16x32_bf16(a0, b1, acc[0][1], 0, 0, 0);
      acc[0][2] = __builtin_amdgcn_mfma_f32_16x16x32_bf16(a0, b2, acc[0][2], 0, 0, 0);
      acc[0][3] = __builtin_amdgcn_mfma_f32_16x16x32_bf16(a0, b3, acc[0][3], 0, 0, 0);
      acc[1][0] = __builtin_amdgcn_mfma_f32_16x16x32_bf16(a1, b0, acc[1][0], 0, 0, 0);
      acc[1][1] = __builtin_amdgcn_mfma_f32_16x16x32_bf16(a1, b1, acc[1][1], 0, 0, 0);
      acc[1][2] = __builtin_amdgcn_mfma_f32_16x16x32_bf16(a1, b2, acc[1][2], 0, 0, 0);
      acc[1][3] = __builtin_amdgcn_mfma_f32_16x16x32_bf16(a1, b3, acc[1][3], 0, 0, 0);
    }

    int cbase = ct*64;
    if (!POOL){
      #pragma unroll
      for (int rf=0;rf<2;rf++){
        int rbase = r0 + 32*w + 16*rf + 4*(l >> 4);
        #pragma unroll
        for (int cf=0;cf<4;cf++){
          int c = cbase + 16*cf + (l & 15);
          if (c >= ldout) continue;
          float bv = (c < NC) ? bias[c] : 0.f;
          #pragma unroll
          for (int r=0;r<4;r++){
            int rr = rbase + r;
            if (rr < n){
              float v = (c < NC) ? fmaxf(acc[rf][cf][r] + bv, 0.f) : 0.f;
              out[(size_t)rr*ldout + c] = f2bf(v);
            }
          }
        }
      }
    } else {
      int g0 = batch[r0];
      #pragma unroll
      for (int rf=0;rf<2;rf++){
        int rbase = r0 + 32*w + 16*rf + 4*(l >> 4);
        #pragma unroll
        for (int cf=0;cf<4;cf++){
          int c = cbase + 16*cf + (l & 15);
          if (c >= NC) continue;
          float bv = bias[c];
          int curgi = -1; float m = 0.f;
          #pragma unroll
          for (int r=0;r<4;r++){
            int rr = rbase + r;
            if (rr < n){
              int gi = batch[rr] - g0; if (gi > 1) gi = 1;
              float v = fmaxf(acc[rf][cf][r] + bv, 0.f);
              if (gi != curgi){
                if (curgi >= 0 && m > 0.f) atomicMax(&pmax[curgi][16*cf + (l&15)], __float_as_uint(m));
                curgi = gi; m = v;
              } else m = fmaxf(m, v);
            }
          }
          if (curgi >= 0 && m > 0.f) atomicMax(&pmax[curgi][16*cf + (l&15)], __float_as_uint(m));
        }
      }
      __syncthreads();
      if (tid < 128){
        int gi = tid >> 6, cc = tid & 63;
        unsigned v = pmax[gi][cc];
        int gg = g0 + gi;
        if (v != 0u && (cbase + cc) < NC && gg < G)
          atomicMax(&gpool[(size_t)gg*ldg + (cbase + cc)], v);
      }
    }
  }
}

// ---------------- bf16 MFMA GEMM with BK=64 K-loop (head layers, f32 in/out) ----------------

__global__ __launch_bounds__(256) void k_gemm_kloop(
    const float* __restrict__ A, int lda, int Ktot,
    const u16* __restrict__ Wt, int ldw,
    const float* __restrict__ bias,
    float* __restrict__ out, int ldout, int NC,
    int n, int relu)
{
  constexpr int SA = 72, SW = 72;
  __shared__ u16 As[128*SA];
  __shared__ u16 Ws[64*SW];
  int tid = threadIdx.x;
  int r0 = blockIdx.x * 128, c0 = blockIdx.y * 64;
  int w = tid >> 6, l = tid & 63;

  f32x4 acc[2][4];
  #pragma unroll
  for (int a=0;a<2;a++)
    #pragma unroll
    for (int b=0;b<4;b++) acc[a][b] = (f32x4){0.f,0.f,0.f,0.f};

  const u16* Ab = &As[(32*w + (l & 15))*SA + (l >> 4)*8];
  const u16* Bb = &Ws[(l & 15)*SW + (l >> 4)*8];

  for (int k0 = 0; k0 < Ktot; k0 += 64){
    #pragma unroll
    for (int i=0;i<8;i++){
      int idx = tid + 256*i;
      int r = idx >> 4, c4 = idx & 15;
      float4 v = make_float4(0.f,0.f,0.f,0.f);
      if (r0 + r < n) v = *(const float4*)&A[(size_t)(r0+r)*lda + k0 + 4*c4];
      unsigned p01 = (unsigned)f2bf(v.x) | ((unsigned)f2bf(v.y) << 16);
      unsigned p23 = (unsigned)f2bf(v.z) | ((unsigned)f2bf(v.w) << 16);
      *(uint2*)&As[r*SA + 4*c4] = make_uint2(p01, p23);
    }
    #pragma unroll
    for (int i=0;i<2;i++){
      int idx = tid + 256*i;
      int wr = idx >> 3, wk = idx & 7;
      short8v wv = *(const short8v*)&Wt[(size_t)(c0+wr)*ldw + k0 + 8*wk];
      *(short8v*)&Ws[wr*SW + 8*wk] = wv;
    }
    __syncthreads();
    #pragma unroll
    for (int ks = 0; ks < 2; ++ks){
      short8v a0 = *(const short8v*)(Ab + ks*32);
      short8v a1 = *(const short8v*)(Ab + 16*SA + ks*32);
      short8v b0 = *(const short8v*)(Bb + ks*32);
      short8v b1 = *(const short8v*)(Bb + 16*SW + ks*32);
      short8v b2 = *(const short8v*)(Bb + 32*SW + ks*32);
      short8v b3 = *(const short8v*)(Bb + 48*SW + ks*32);
      acc[0][0] = __builtin_amdgcn_mfma_f32_16x16x32_bf16(a0, b0, acc[0][0], 0, 0, 0);
      acc[0][1] = __builtin_amdgcn_mfma_f32_16x16x32_bf16(a0, b1, acc[0][1], 0, 0, 0);
      acc[0][2] = __builtin_amdgcn_mfma_f32_16x16x32_bf16(a0, b2, acc[0][2], 0, 0, 0);
      acc[0][3] = __builtin_amdgcn_mfma_f32_16x16x32_bf16(a0, b3, acc[0][3], 0, 0, 0);
      acc[1][0] = __builtin_amdgcn_mfma_f32_16x16x32_bf16(a1, b0, acc[1][0], 0, 0, 0);
      acc[1][1] = __builtin_amdgcn_mfma_f32_16x16x32_bf16(a1, b1, acc[1][1], 0, 0, 0);
      acc[1][2] = __builtin_amdgcn_mfma_f32_16x16x32_bf16(a1, b2, acc[1][2], 0, 0, 0);
      acc[1][3] = __builtin_amdgcn_mfma_f32_16x16x32_bf16(a1, b3, acc[1][3], 0, 0, 0);
    }
    __syncthreads();
  }

  #pragma unroll
  for (int rf=0;rf<2;rf++){
    int rbase = r0 + 32*w + 16*rf + 4*(l >> 4);
    #pragma unroll
    for (int cf=0;cf<4;cf++){
      int c = c0 + 16*cf + (l & 15);
      if (c >= NC) continue;
      float bv = bias[c];
      #pragma unroll
      for (int r=0;r<4;r++){
        int rr = rbase + r;
        if (rr < n){
          float v = acc[rf][cf][r] + bv;
          if (relu) v = fmaxf(v, 0.f);
          out[(size_t)rr*ldout + c] = v;
        }
      }
    }
  }
}

// ---------------- launcher ----------------

extern "C" void kernel_launch(void* const* d_in, const int* in_sizes, int n_in,
                              void* d_out, int out_size, void* d_ws, size_t ws_size,
                              hipStream_t stream)
{
  const float* x   = (const float*)d_in[0];
  const int*   ei  = (const int*)d_in[1];
  const int*   batch = (const int*)d_in[2];
  const float* W1  = (const float*)d_in[3]; const float* b1  = (const float*)d_in[4];
  const float* W2  = (const float*)d_in[5]; const float* b2  = (const float*)d_in[6];
  const float* W3  = (const float*)d_in[7]; const float* b3  = (const float*)d_in[8];
  const float* Wg1 = (const float*)d_in[9]; const float* bg1 = (const float*)d_in[10];
  const float* Wg2 = (const float*)d_in[11]; const float* bg2 = (const float*)d_in[12];
  float* out = (float*)d_out;

  const int F1 = 75;
  int n = in_sizes[0] / F1;          // 100000
  int E = in_sizes[1] / 2;           // 800000
  int G = out_size / 128;            // 512
  const int* row = ei;
  const int* col = ei + E;

  char* ws = (char*)d_ws;
  size_t off = 0;
  auto alloc = [&](size_t bytes){ size_t o = off; off += (bytes + 255) & ~(size_t)255; return o; };
  u16*   xb    = (u16*)  (ws + alloc((size_t)n*80*2));   // padded bf16 x; aliased as h1 later
  u16*   qb    = (u16*)  (ws + alloc((size_t)n*160*2));  // propagated features (stride 80 or 160)
  u16*   h2b   = (u16*)  (ws + alloc((size_t)n*160*2));
  float* dinv  = (float*)(ws + alloc((size_t)n*4));
  int*   indeg = (int*)  (ws + alloc((size_t)n*4));
  int*   rp    = (int*)  (ws + alloc((size_t)(n+1)*4));
  int*   nxt   = (int*)  (ws + alloc((size_t)n*4));
  int*   csr   = (int*)  (ws + alloc((size_t)E*4));
  int*   bsums = (int*)  (ws + alloc(1024*4));
  unsigned* g  = (unsigned*)(ws + alloc((size_t)G*320*4));
  float* gh    = (float*)(ws + alloc((size_t)G*1024*4));
  u16* Wt1  = (u16*)(ws + alloc((size_t)128*96*2));
  u16* Wt2  = (u16*)(ws + alloc((size_t)192*96*2));
  u16* Wt3  = (u16*)(ws + alloc((size_t)320*160*2));
  u16* Wg1t = (u16*)(ws + alloc((size_t)1024*320*2));
  u16* Wg2t = (u16*)(ws + alloc((size_t)128*1024*2));
  u16* h1b = xb;   // alias: xb dead after prop1

  hipMemsetAsync(indeg, 0, (size_t)n*4, stream);
  hipMemsetAsync(g, 0, (size_t)G*320*4, stream);

  k_deg<<<(E+255)/256, 256, 0, stream>>>(col, indeg, E);
  k_dinv<<<(n+255)/256, 256, 0, stream>>>(indeg, dinv, n);

  int nb = (n + 1023) / 1024;
  k_scan1<<<nb, 256, 0, stream>>>(indeg, rp, bsums, n);
  k_scan2<<<1, 128, 0, stream>>>(bsums, rp, nb, n);
  k_scan3<<<(n+255)/256, 256, 0, stream>>>(rp, nxt, bsums, n);
  k_scatter<<<(E+255)/256, 256, 0, stream>>>(row, col, nxt, csr, E);

  k_padb<<<4096, 256, 0, stream>>>(x, xb, n);
  k_wt<<<(128*96+255)/256, 256, 0, stream>>>(W1, Wt1, 75, 75, 96, 128);
  k_wt<<<(192*96+255)/256, 256, 0, stream>>>(W2, Wt2, 75, 150, 96, 192);
  k_wt<<<(320*160+255)/256, 256, 0, stream>>>(W3, Wt3, 150, 300, 160, 320);
  k_wt<<<(1024*320+255)/256, 256, 0, stream>>>(Wg1, Wg1t, 300, 1024, 320, 1024);
  k_wt<<<(128*1024+255)/256, 256, 0, stream>>>(Wg2, Wg2t, 1024, 128, 1024, 128);

  int mb = (n + 127) / 128;   // 782

  // layer 1: q = Ahat xb ; h1 = relu(q@W1+b1)
  k_prop_bf<80><<<(n+24)/25, 256, 0, stream>>>(xb, dinv, rp, csr, qb, n);
  k_gemm_bf<96,80,0><<<mb, 256, 0, stream>>>(qb, Wt1, b1, h1b, 80, 75, 2,
                                             nullptr, nullptr, 0, n, G);
  // layer 2
  k_prop_bf<80><<<(n+24)/25, 256, 0, stream>>>(h1b, dinv, rp, csr, qb, n);
  k_gemm_bf<96,80,0><<<mb, 256, 0, stream>>>(qb, Wt2, b2, h2b, 160, 150, 3,
                                             nullptr, nullptr, 0, n, G);
  // layer 3 + fused relu + segment-max pool -> g (f32 bits, stride 320)
  k_prop_bf<160><<<(n+11)/12, 256, 0, stream>>>(h2b, dinv, rp, csr, qb, n);
  k_gemm_bf<160,160,1><<<mb, 256, 0, stream>>>(qb, Wt3, b3, nullptr, 0, 300, 5,
                                               batch, g, 320, n, G);
  // head 1: gh = relu(g @ Wg1 + bg1)
  {
    dim3 grid(G/128, 1024/64);
    k_gemm_kloop<<<grid, 256, 0, stream>>>((const float*)g, 320, 320, Wg1t, 320, bg1,
                                           gh, 1024, 1024, G, 1);
  }
  // head 2: out = gh @ Wg2 + bg2
  {
    dim3 grid(G/128, 128/64);
    k_gemm_kloop<<<grid, 256, 0, stream>>>(gh, 1024, 1024, Wg2t, 1024, bg2,
                                           out, 128, 128, G, 0);
  }
}